// Round 8
// baseline (130.266 us; speedup 1.0000x reference)
//
#include <hip/hip_runtime.h>
#include <hip/hip_fp16.h>
#include <math.h>

#define NUM_VARS 64
#define KK       32
#define NUM_CATS 256
#define LL       4
#define EE       16384
#define NN       8192
#define CC       4
#define BB       1024
#define NUM_INPUT 2048              // NUM_VARS * KK
#define RES_ROWS  18432             // input + L0 + L1 resident in LDS
#define RES_BYTES (RES_ROWS * 8)    // 147456 (8 B/row = 4 cols fp16)
#define THREADS   1024
// LDS: rows (147456 B) + red scratch (512 B) + cats (1024 B)
#define LDS_BYTES (RES_BYTES + 512 + 1024)

#define LOG2E 1.4426950408889634f
#define LN2   0.6931471805599453f

#if __has_builtin(__builtin_amdgcn_exp2f)
#define EXP2(x) __builtin_amdgcn_exp2f(x)
#else
#define EXP2(x) exp2f(x)
#endif
#if __has_builtin(__builtin_amdgcn_logf)
#define LOG2(x) __builtin_amdgcn_logf(x)
#else
#define LOG2(x) log2f(x)
#endif

// Per-layer magnitude biases (log2 domain). Stored row = true - BIAS[layer].
#define B_IN  (-9.0f)
#define B_L0  (-19.0f)
#define B_L1  (-39.0f)
#define B_L2  (-79.0f)

__device__ __forceinline__ float child_bias(int row) {
    if (row < NUM_INPUT) return B_IN;
    int l = (row - NUM_INPUT) >> 13;
    return l == 0 ? B_L0 : (l == 1 ? B_L1 : B_L2);
}

// ---------------------------------------------------------------------------
// Prep: collapse sum_ch_ids -> prod_ids into 8 byte offsets (row*8) per node;
// weights -> base-2 domain with bias folding; root_logw folded into layer 3.
// ---------------------------------------------------------------------------
__global__ void prep_kernel(const int* __restrict__ prod_ids,    // L x E x 2
                            const int* __restrict__ sum_ch_ids,  // L x N x C
                            const float* __restrict__ sum_logw,  // L x N x C
                            const float* __restrict__ root_logw, // N
                            int4* __restrict__ recA,             // L*N x 2
                            float4* __restrict__ recB)           // L*N
{
    int idx = blockIdx.x * 64 + threadIdx.x;      // 0 .. L*N-1
    int l = idx >> 13;
    int n = idx & (NN - 1);
    const int*  sch  = sum_ch_ids + (size_t)idx * CC;
    const int2* prod = (const int2*)prod_ids + (size_t)l * EE;
    int2 p0 = prod[sch[0]];
    int2 p1 = prod[sch[1]];
    int2 p2 = prod[sch[2]];
    int2 p3 = prod[sch[3]];
    recA[(size_t)idx * 2]     = make_int4(p0.x << 3, p0.y << 3, p1.x << 3, p1.y << 3);
    recA[(size_t)idx * 2 + 1] = make_int4(p2.x << 3, p2.y << 3, p3.x << 3, p3.y << 3);

    const float nodeB[4] = {B_L0, B_L1, B_L2, 0.0f};
    float r = (l == 3) ? root_logw[n] : 0.0f;
    const float* w = sum_logw + (size_t)idx * CC;
    float4 wb;
    wb.x = (w[0] + r) * LOG2E + child_bias(p0.x) + child_bias(p0.y) - nodeB[l];
    wb.y = (w[1] + r) * LOG2E + child_bias(p1.x) + child_bias(p1.y) - nodeB[l];
    wb.z = (w[2] + r) * LOG2E + child_bias(p2.x) + child_bias(p2.y) - nodeB[l];
    wb.w = (w[3] + r) * LOG2E + child_bias(p3.x) + child_bias(p3.y) - nodeB[l];
    recB[idx] = wb;
}

// base-2 logsumexp of 4
__device__ __forceinline__ float lse4_2(float a, float b, float c, float d) {
    float m = fmaxf(fmaxf(fmaxf(a, b), c), d);
    float s = EXP2(a - m) + EXP2(b - m) + EXP2(c - m) + EXP2(d - m);
    return m + LOG2(s);
}

__device__ __forceinline__ unsigned pack2(float a, float b) {
    __half2 h = __floats2half2_rn(a, b);
    union { __half2 h; unsigned u; } cv; cv.h = h; return cv.u;
}
__device__ __forceinline__ float2 unpack2(unsigned u) {
    union { unsigned u; __half2 h; } cv; cv.u = u;
    return __half22float2(cv.h);
}

// gather 8 children (uint2 = 4 cols fp16) + compute 4-column node values
__device__ __forceinline__ float4 node4(const uint2 h[8], float4 w) {
    // child-pair sums per column-pair
    float2 a, b;
    float2 p01[4], p23[4];
#pragma unroll
    for (int c = 0; c < 4; ++c) {
        a = unpack2(h[2 * c].x); b = unpack2(h[2 * c + 1].x);
        p01[c] = make_float2(a.x + b.x, a.y + b.y);
        a = unpack2(h[2 * c].y); b = unpack2(h[2 * c + 1].y);
        p23[c] = make_float2(a.x + b.x, a.y + b.y);
    }
    float4 r;
    r.x = lse4_2(w.x + p01[0].x, w.y + p01[1].x, w.z + p01[2].x, w.w + p01[3].x);
    r.y = lse4_2(w.x + p01[0].y, w.y + p01[1].y, w.z + p01[2].y, w.w + p01[3].y);
    r.z = lse4_2(w.x + p23[0].x, w.y + p23[1].x, w.z + p23[2].x, w.w + p23[3].x);
    r.w = lse4_2(w.x + p23[0].y, w.y + p23[1].y, w.z + p23[2].y, w.w + p23[3].y);
    return r;
}

// ---------------------------------------------------------------------------
// Mega-kernel: one block = FOUR batch columns (fp16x4 = 8 B per row).
// {input, L0, L1} resident in LDS (144 KB); L2 streams to global (per-block
// 64 KB, XCD-L2 resident); L3 gathers via per-lane generic-pointer select.
// All values base-2 log domain with per-layer bias folding (done in prep).
// ---------------------------------------------------------------------------
__global__ __launch_bounds__(THREADS, 4)
void circuit_kernel(const int* __restrict__ inputs,          // B x NUM_VARS
                    const float* __restrict__ input_logp,    // V x K x CATS
                    const int4* __restrict__ recA,           // L*N x 2
                    const float4* __restrict__ recB,         // L*N
                    uint2* __restrict__ gL2all,              // B/4 x NN
                    float* __restrict__ out)                 // B
{
    extern __shared__ float lds[];
    uint2* rows64 = (uint2*)lds;
    float* red  = lds + RES_BYTES / 4;          // 128 floats (16 waves x 8)
    int*   cats = (int*)(red + 128);            // 256 ints (4 cols x 64 vars)

    int b4 = blockIdx.x * 4;
    int t = threadIdx.x;
    uint2* g2 = gL2all + (size_t)blockIdx.x * NN;

    if (t < 256) cats[t] = inputs[(b4 + (t >> 6)) * NUM_VARS + (t & 63)];
    __syncthreads();

    // ---- input layer: 4 category gathers per row, pack to fp16x4
#pragma unroll
    for (int i = 0; i < NUM_INPUT / THREADS; ++i) {
        int idx = t + i * THREADS;
        int v = idx >> 5;
        const float* base = input_logp + (size_t)idx * NUM_CATS;
        float f0 = fmaf(base[cats[v]],        LOG2E, -B_IN);
        float f1 = fmaf(base[cats[64 + v]],   LOG2E, -B_IN);
        float f2 = fmaf(base[cats[128 + v]],  LOG2E, -B_IN);
        float f3 = fmaf(base[cats[192 + v]],  LOG2E, -B_IN);
        rows64[idx] = make_uint2(pack2(f0, f1), pack2(f2, f3));
    }
    __syncthreads();

    // ---- layers 0..2: pure-LDS gather; L0/L1 -> LDS, L2 -> global stream
    for (int l = 0; l < 3; ++l) {
        const int4*   ra = recA + (size_t)l * NN * 2;
        const float4* rb = recB + (size_t)l * NN;
        uint2* dstl = rows64 + NUM_INPUT + l * NN;   // used for l<2
#pragma unroll 2
        for (int i = 0; i < NN / THREADS; ++i) {
            int n = t + i * THREADS;
            int4 r0 = ra[(size_t)n * 2];
            int4 r1 = ra[(size_t)n * 2 + 1];
            float4 w = rb[n];
            uint2 h[8];
            h[0] = *(const uint2*)((const char*)lds + r0.x);
            h[1] = *(const uint2*)((const char*)lds + r0.y);
            h[2] = *(const uint2*)((const char*)lds + r0.z);
            h[3] = *(const uint2*)((const char*)lds + r0.w);
            h[4] = *(const uint2*)((const char*)lds + r1.x);
            h[5] = *(const uint2*)((const char*)lds + r1.y);
            h[6] = *(const uint2*)((const char*)lds + r1.z);
            h[7] = *(const uint2*)((const char*)lds + r1.w);
            float4 r = node4(h, w);
            uint2 packed = make_uint2(pack2(r.x, r.y), pack2(r.z, r.w));
            if (l < 2) dstl[n] = packed;
            else       g2[n]   = packed;
        }
        __syncthreads();   // also drains vmcnt(0) after L2 global stores
    }

    // ---- layer 3 + root accumulate; children from LDS or global-L2 rows
    {
        const int4*   ra = recA + (size_t)3 * NN * 2;
        const float4* rb = recB + (size_t)3 * NN;
        uintptr_t lb = (uintptr_t)lds;
        uintptr_t gb = (uintptr_t)g2 - (uintptr_t)RES_BYTES;
        float m[4], s[4];
#pragma unroll
        for (int c = 0; c < 4; ++c) { m[c] = -INFINITY; s[c] = 0.0f; }
#pragma unroll 2
        for (int i = 0; i < NN / THREADS; ++i) {
            int n = t + i * THREADS;
            int4 r0 = ra[(size_t)n * 2];
            int4 r1 = ra[(size_t)n * 2 + 1];
            float4 w = rb[n];
            uint2 h[8];
            h[0] = *(const uint2*)(((unsigned)r0.x < RES_BYTES ? lb : gb) + (unsigned)r0.x);
            h[1] = *(const uint2*)(((unsigned)r0.y < RES_BYTES ? lb : gb) + (unsigned)r0.y);
            h[2] = *(const uint2*)(((unsigned)r0.z < RES_BYTES ? lb : gb) + (unsigned)r0.z);
            h[3] = *(const uint2*)(((unsigned)r0.w < RES_BYTES ? lb : gb) + (unsigned)r0.w);
            h[4] = *(const uint2*)(((unsigned)r1.x < RES_BYTES ? lb : gb) + (unsigned)r1.x);
            h[5] = *(const uint2*)(((unsigned)r1.y < RES_BYTES ? lb : gb) + (unsigned)r1.y);
            h[6] = *(const uint2*)(((unsigned)r1.z < RES_BYTES ? lb : gb) + (unsigned)r1.z);
            h[7] = *(const uint2*)(((unsigned)r1.w < RES_BYTES ? lb : gb) + (unsigned)r1.w);
            float4 v = node4(h, w);
            float vv[4] = {v.x, v.y, v.z, v.w};
#pragma unroll
            for (int c = 0; c < 4; ++c) {
                float tm = fmaxf(m[c], vv[c]);
                s[c] = s[c] * EXP2(m[c] - tm) + EXP2(vv[c] - tm);
                m[c] = tm;
            }
        }
        // wave reduce (64 lanes), 4 columns
#pragma unroll
        for (int off = 32; off >= 1; off >>= 1) {
#pragma unroll
            for (int c = 0; c < 4; ++c) {
                float om = __shfl_xor(m[c], off), os = __shfl_xor(s[c], off);
                float tm = fmaxf(m[c], om);
                s[c] = s[c] * EXP2(m[c] - tm) + os * EXP2(om - tm);
                m[c] = tm;
            }
        }
        int wid = t >> 6;
        if ((t & 63) == 0) {
#pragma unroll
            for (int c = 0; c < 4; ++c) {
                red[wid * 8 + c * 2]     = m[c];
                red[wid * 8 + c * 2 + 1] = s[c];
            }
        }
        __syncthreads();
        if (t < 4) {                      // one thread per column
            int c = t;
            float M = -INFINITY;
#pragma unroll
            for (int wv = 0; wv < THREADS / 64; ++wv)
                M = fmaxf(M, red[wv * 8 + c * 2]);
            float S = 0.0f;
#pragma unroll
            for (int wv = 0; wv < THREADS / 64; ++wv)
                S += red[wv * 8 + c * 2 + 1] * EXP2(red[wv * 8 + c * 2] - M);
            out[b4 + c] = (M + LOG2(S)) * LN2;
        }
    }
}

extern "C" void kernel_launch(void* const* d_in, const int* in_sizes, int n_in,
                              void* d_out, int out_size, void* d_ws, size_t ws_size,
                              hipStream_t stream) {
    const int*   inputs      = (const int*)d_in[0];
    const float* input_logp  = (const float*)d_in[1];
    const int*   prod_ids    = (const int*)d_in[2];
    const int*   sum_ch_ids  = (const int*)d_in[3];
    const float* sum_logw    = (const float*)d_in[4];
    const float* root_logw   = (const float*)d_in[5];
    float* out = (float*)d_out;

    int4*   recA  = (int4*)d_ws;                            // [L*N][2] int4 (1 MB)
    float4* recB  = (float4*)(recA + (size_t)LL * NN * 2);  // [L*N] float4 (512 KB)
    uint2*  gL2all = (uint2*)(recB + (size_t)LL * NN);      // [B/4][NN] uint2 (16 MB)

    static bool attr_done = false;
    if (!attr_done) {
        hipFuncSetAttribute((const void*)circuit_kernel,
                            hipFuncAttributeMaxDynamicSharedMemorySize, LDS_BYTES);
        attr_done = true;
    }

    prep_kernel<<<(LL * NN) / 64, 64, 0, stream>>>(
        prod_ids, sum_ch_ids, sum_logw, root_logw, recA, recB);

    circuit_kernel<<<BB / 4, THREADS, LDS_BYTES, stream>>>(
        inputs, input_logp, recA, recB, gL2all, out);
}

// Round 10
// 122.035 us; speedup vs baseline: 1.0674x; 1.0674x over previous
//
#include <hip/hip_runtime.h>
#include <hip/hip_fp16.h>
#include <math.h>

#define NUM_VARS 64
#define KK       32
#define NUM_CATS 256
#define LL       4
#define EE       16384
#define NN       8192
#define CC       4
#define BB       1024
#define NUM_INPUT 2048              // NUM_VARS * KK
#define RES_ROWS  18432             // input + L0 + L1 resident in LDS
#define RES_BYTES (RES_ROWS * 8)    // 147456 (8 B/row = 4 cols fp16)
#define THREADS   1024
// LDS: rows (147456 B) + red scratch (512 B) + cats (1024 B)
#define LDS_BYTES (RES_BYTES + 512 + 1024)

#define LOG2E 1.4426950408889634f
#define LN2   0.6931471805599453f

#if __has_builtin(__builtin_amdgcn_exp2f)
#define EXP2(x) __builtin_amdgcn_exp2f(x)
#else
#define EXP2(x) exp2f(x)
#endif
#if __has_builtin(__builtin_amdgcn_logf)
#define LOG2(x) __builtin_amdgcn_logf(x)
#else
#define LOG2(x) log2f(x)
#endif

// Flattened per-layer magnitude biases (log2 domain). Stored row = true - B.
// Flat schedule keeps BOTH stored values and mixed-depth product args small
// in fp16 regardless of whether shallow or deep pairs dominate each node.
#define B_IN  (-9.0f)
#define B_L0  (-18.0f)
#define B_L1  (-26.0f)
#define B_L2  (-31.0f)
#define B_RT  (-64.0f)   // root un-bias, applied exactly at the output

__device__ __forceinline__ float child_bias(int row) {
    if (row < NUM_INPUT) return B_IN;
    int l = (row - NUM_INPUT) >> 13;
    return l == 0 ? B_L0 : (l == 1 ? B_L1 : B_L2);
}

__device__ __forceinline__ __half2 u2h(unsigned u) {
    union { unsigned u; __half2 h; } c; c.u = u; return c.h;
}
__device__ __forceinline__ unsigned h2u(__half2 h) {
    union { __half2 h; unsigned u; } c; c.h = h; return c.u;
}

// ROCm 7.2 has no __hmax2 — emit the packed max directly (VOP3P).
__device__ __forceinline__ __half2 hmax2(__half2 a, __half2 b) {
    unsigned r, ua = h2u(a), ub = h2u(b);
    asm("v_pk_max_f16 %0, %1, %2" : "=v"(r) : "v"(ua), "v"(ub));
    return u2h(r);
}

// ---------------------------------------------------------------------------
// Prep: collapse sum_ch_ids -> prod_ids into 8 byte offsets (row*8) per node;
// weights -> base-2 domain, bias-folded, duplicated per column-pair as fp16x2
// words (uint4 = 4 children). root_logw folded into layer 3; root un-bias
// hoisted out as the exact constant B_RT.
// ---------------------------------------------------------------------------
__global__ void prep_kernel(const int* __restrict__ prod_ids,    // L x E x 2
                            const int* __restrict__ sum_ch_ids,  // L x N x C
                            const float* __restrict__ sum_logw,  // L x N x C
                            const float* __restrict__ root_logw, // N
                            int4* __restrict__ recA,             // L*N x 2
                            uint4* __restrict__ recBh)           // L*N
{
    int idx = blockIdx.x * 64 + threadIdx.x;      // 0 .. L*N-1
    int l = idx >> 13;
    int n = idx & (NN - 1);
    const int*  sch  = sum_ch_ids + (size_t)idx * CC;
    const int2* prod = (const int2*)prod_ids + (size_t)l * EE;
    int2 p0 = prod[sch[0]];
    int2 p1 = prod[sch[1]];
    int2 p2 = prod[sch[2]];
    int2 p3 = prod[sch[3]];
    recA[(size_t)idx * 2]     = make_int4(p0.x << 3, p0.y << 3, p1.x << 3, p1.y << 3);
    recA[(size_t)idx * 2 + 1] = make_int4(p2.x << 3, p2.y << 3, p3.x << 3, p3.y << 3);

    const float nodeB[4] = {B_L0, B_L1, B_L2, B_RT};
    float r = (l == 3) ? root_logw[n] : 0.0f;
    const float* w = sum_logw + (size_t)idx * CC;
    float f0 = (w[0] + r) * LOG2E + child_bias(p0.x) + child_bias(p0.y) - nodeB[l];
    float f1 = (w[1] + r) * LOG2E + child_bias(p1.x) + child_bias(p1.y) - nodeB[l];
    float f2 = (w[2] + r) * LOG2E + child_bias(p2.x) + child_bias(p2.y) - nodeB[l];
    float f3 = (w[3] + r) * LOG2E + child_bias(p3.x) + child_bias(p3.y) - nodeB[l];
    recBh[idx] = make_uint4(h2u(__half2half2(__float2half_rn(f0))),
                            h2u(__half2half2(__float2half_rn(f1))),
                            h2u(__half2half2(__float2half_rn(f2))),
                            h2u(__half2half2(__float2half_rn(f3))));
}

// packed base-2 logsumexp of 4 (two columns per __half2 lane-pair)
__device__ __forceinline__ __half2 lse4h(__half2 x0, __half2 x1,
                                         __half2 x2, __half2 x3) {
    __half2 m = hmax2(hmax2(x0, x1), hmax2(x2, x3));
    __half2 s = __hadd2(__hadd2(h2exp2(__hsub2(x0, m)), h2exp2(__hsub2(x1, m))),
                        __hadd2(h2exp2(__hsub2(x2, m)), h2exp2(__hsub2(x3, m))));
    return __hadd2(m, h2log2(s));
}

// gather-8 -> packed node value (4 cols in uint2)
__device__ __forceinline__ uint2 node4h(const uint2 h[8], uint4 wu) {
    __half2 xa0 = __hadd2(__hadd2(u2h(h[0].x), u2h(h[1].x)), u2h(wu.x));
    __half2 xa1 = __hadd2(__hadd2(u2h(h[2].x), u2h(h[3].x)), u2h(wu.y));
    __half2 xa2 = __hadd2(__hadd2(u2h(h[4].x), u2h(h[5].x)), u2h(wu.z));
    __half2 xa3 = __hadd2(__hadd2(u2h(h[6].x), u2h(h[7].x)), u2h(wu.w));
    __half2 xb0 = __hadd2(__hadd2(u2h(h[0].y), u2h(h[1].y)), u2h(wu.x));
    __half2 xb1 = __hadd2(__hadd2(u2h(h[2].y), u2h(h[3].y)), u2h(wu.y));
    __half2 xb2 = __hadd2(__hadd2(u2h(h[4].y), u2h(h[5].y)), u2h(wu.z));
    __half2 xb3 = __hadd2(__hadd2(u2h(h[6].y), u2h(h[7].y)), u2h(wu.w));
    uint2 res;
    res.x = h2u(lse4h(xa0, xa1, xa2, xa3));
    res.y = h2u(lse4h(xb0, xb1, xb2, xb3));
    return res;
}

// ---------------------------------------------------------------------------
// Mega-kernel: one block = FOUR batch columns (fp16x4 = 8 B per row).
// {input, L0, L1} resident in LDS (144 KB); L2 streams to global; L3 gathers
// via per-lane generic-pointer select. Node math fully packed fp16; root
// accumulation f32. Base-2 log domain; bias folding done in prep.
// ---------------------------------------------------------------------------
__global__ __launch_bounds__(THREADS, 4)
void circuit_kernel(const int* __restrict__ inputs,          // B x NUM_VARS
                    const float* __restrict__ input_logp,    // V x K x CATS
                    const int4* __restrict__ recA,           // L*N x 2
                    const uint4* __restrict__ recBh,         // L*N
                    uint2* __restrict__ gL2all,              // B/4 x NN
                    float* __restrict__ out)                 // B
{
    extern __shared__ float lds[];
    uint2* rows64 = (uint2*)lds;
    float* red  = lds + RES_BYTES / 4;          // 128 floats (16 waves x 8)
    int*   cats = (int*)(red + 128);            // 256 ints (4 cols x 64 vars)

    int b4 = blockIdx.x * 4;
    int t = threadIdx.x;
    uint2* g2 = gL2all + (size_t)blockIdx.x * NN;

    if (t < 256) cats[t] = inputs[(b4 + (t >> 6)) * NUM_VARS + (t & 63)];
    __syncthreads();

    // ---- input layer: 4 category gathers per row, pack to fp16x4
#pragma unroll
    for (int i = 0; i < NUM_INPUT / THREADS; ++i) {
        int idx = t + i * THREADS;
        int v = idx >> 5;
        const float* base = input_logp + (size_t)idx * NUM_CATS;
        float f0 = fmaf(base[cats[v]],        LOG2E, -B_IN);
        float f1 = fmaf(base[cats[64 + v]],   LOG2E, -B_IN);
        float f2 = fmaf(base[cats[128 + v]],  LOG2E, -B_IN);
        float f3 = fmaf(base[cats[192 + v]],  LOG2E, -B_IN);
        rows64[idx] = make_uint2(h2u(__floats2half2_rn(f0, f1)),
                                 h2u(__floats2half2_rn(f2, f3)));
    }
    __syncthreads();

    // ---- layers 0..2: pure-LDS gather; L0/L1 -> LDS, L2 -> global stream
    for (int l = 0; l < 3; ++l) {
        const int4*  ra = recA  + (size_t)l * NN * 2;
        const uint4* rb = recBh + (size_t)l * NN;
        uint2* dstl = rows64 + NUM_INPUT + l * NN;   // used for l<2
#pragma unroll 2
        for (int i = 0; i < NN / THREADS; ++i) {
            int n = t + i * THREADS;
            int4 r0 = ra[(size_t)n * 2];
            int4 r1 = ra[(size_t)n * 2 + 1];
            uint4 wu = rb[n];
            uint2 h[8];
            h[0] = *(const uint2*)((const char*)lds + r0.x);
            h[1] = *(const uint2*)((const char*)lds + r0.y);
            h[2] = *(const uint2*)((const char*)lds + r0.z);
            h[3] = *(const uint2*)((const char*)lds + r0.w);
            h[4] = *(const uint2*)((const char*)lds + r1.x);
            h[5] = *(const uint2*)((const char*)lds + r1.y);
            h[6] = *(const uint2*)((const char*)lds + r1.z);
            h[7] = *(const uint2*)((const char*)lds + r1.w);
            uint2 packed = node4h(h, wu);
            if (l < 2) dstl[n] = packed;
            else       g2[n]   = packed;
        }
        __syncthreads();   // also drains stores before next layer reads
    }

    // ---- layer 3 + root accumulate; children from LDS or global-L2 rows
    {
        const int4*  ra = recA  + (size_t)3 * NN * 2;
        const uint4* rb = recBh + (size_t)3 * NN;
        uintptr_t lb = (uintptr_t)lds;
        uintptr_t gb = (uintptr_t)g2 - (uintptr_t)RES_BYTES;
        float m[4], s[4];
#pragma unroll
        for (int c = 0; c < 4; ++c) { m[c] = -INFINITY; s[c] = 0.0f; }
#pragma unroll 2
        for (int i = 0; i < NN / THREADS; ++i) {
            int n = t + i * THREADS;
            int4 r0 = ra[(size_t)n * 2];
            int4 r1 = ra[(size_t)n * 2 + 1];
            uint4 wu = rb[n];
            uint2 h[8];
            h[0] = *(const uint2*)(((unsigned)r0.x < RES_BYTES ? lb : gb) + (unsigned)r0.x);
            h[1] = *(const uint2*)(((unsigned)r0.y < RES_BYTES ? lb : gb) + (unsigned)r0.y);
            h[2] = *(const uint2*)(((unsigned)r0.z < RES_BYTES ? lb : gb) + (unsigned)r0.z);
            h[3] = *(const uint2*)(((unsigned)r0.w < RES_BYTES ? lb : gb) + (unsigned)r0.w);
            h[4] = *(const uint2*)(((unsigned)r1.x < RES_BYTES ? lb : gb) + (unsigned)r1.x);
            h[5] = *(const uint2*)(((unsigned)r1.y < RES_BYTES ? lb : gb) + (unsigned)r1.y);
            h[6] = *(const uint2*)(((unsigned)r1.z < RES_BYTES ? lb : gb) + (unsigned)r1.z);
            h[7] = *(const uint2*)(((unsigned)r1.w < RES_BYTES ? lb : gb) + (unsigned)r1.w);
            uint2 res = node4h(h, wu);
            float2 v01 = __half22float2(u2h(res.x));
            float2 v23 = __half22float2(u2h(res.y));
            float vv[4] = {v01.x, v01.y, v23.x, v23.y};
#pragma unroll
            for (int c = 0; c < 4; ++c) {
                float tm = fmaxf(m[c], vv[c]);
                s[c] = s[c] * EXP2(m[c] - tm) + EXP2(vv[c] - tm);
                m[c] = tm;
            }
        }
        // wave reduce (64 lanes), 4 columns
#pragma unroll
        for (int off = 32; off >= 1; off >>= 1) {
#pragma unroll
            for (int c = 0; c < 4; ++c) {
                float om = __shfl_xor(m[c], off), os = __shfl_xor(s[c], off);
                float tm = fmaxf(m[c], om);
                s[c] = s[c] * EXP2(m[c] - tm) + os * EXP2(om - tm);
                m[c] = tm;
            }
        }
        int wid = t >> 6;
        if ((t & 63) == 0) {
#pragma unroll
            for (int c = 0; c < 4; ++c) {
                red[wid * 8 + c * 2]     = m[c];
                red[wid * 8 + c * 2 + 1] = s[c];
            }
        }
        __syncthreads();
        if (t < 4) {                      // one thread per column
            int c = t;
            float M = -INFINITY;
#pragma unroll
            for (int wv = 0; wv < THREADS / 64; ++wv)
                M = fmaxf(M, red[wv * 8 + c * 2]);
            float S = 0.0f;
#pragma unroll
            for (int wv = 0; wv < THREADS / 64; ++wv)
                S += red[wv * 8 + c * 2 + 1] * EXP2(red[wv * 8 + c * 2] - M);
            out[b4 + c] = (M + LOG2(S) + B_RT) * LN2;
        }
    }
}

extern "C" void kernel_launch(void* const* d_in, const int* in_sizes, int n_in,
                              void* d_out, int out_size, void* d_ws, size_t ws_size,
                              hipStream_t stream) {
    const int*   inputs      = (const int*)d_in[0];
    const float* input_logp  = (const float*)d_in[1];
    const int*   prod_ids    = (const int*)d_in[2];
    const int*   sum_ch_ids  = (const int*)d_in[3];
    const float* sum_logw    = (const float*)d_in[4];
    const float* root_logw   = (const float*)d_in[5];
    float* out = (float*)d_out;

    int4*  recA   = (int4*)d_ws;                            // [L*N][2] int4 (1 MB)
    uint4* recBh  = (uint4*)(recA + (size_t)LL * NN * 2);   // [L*N] uint4 (512 KB)
    uint2* gL2all = (uint2*)(recBh + (size_t)LL * NN);      // [B/4][NN] uint2 (16 MB)

    static bool attr_done = false;
    if (!attr_done) {
        (void)hipFuncSetAttribute((const void*)circuit_kernel,
                                  hipFuncAttributeMaxDynamicSharedMemorySize,
                                  LDS_BYTES);
        attr_done = true;
    }

    prep_kernel<<<(LL * NN) / 64, 64, 0, stream>>>(
        prod_ids, sum_ch_ids, sum_logw, root_logw, recA, recBh);

    circuit_kernel<<<BB / 4, THREADS, LDS_BYTES, stream>>>(
        inputs, input_logp, recA, recBh, gL2all, out);
}